// Round 5
// baseline (407.741 us; speedup 1.0000x reference)
//
#include <hip/hip_runtime.h>
#include <math.h>

#define NORM_C (-8.3255483f)   /* -log(32+4096) */

typedef __attribute__((ext_vector_type(8))) short bf16x8;
typedef __attribute__((ext_vector_type(4))) float f32x4;

union U8 { uint4 q; unsigned u[4]; bf16x8 v; };

__device__ inline unsigned short f2bf_rne(float f) {
    unsigned u = __float_as_uint(f);
    unsigned r = u + 0x7fffu + ((u >> 16) & 1u);
    return (unsigned short)(r >> 16);
}
// pack two floats -> (bf16(hi)<<16)|bf16(lo)
__device__ inline unsigned pack_bf2(float lo, float hi) {
    unsigned a = __float_as_uint(lo) + 0x8000u;
    unsigned b = __float_as_uint(hi) + 0x8000u;
    return __builtin_amdgcn_perm(b, a, 0x07060302u);
}

// ---------------------------------------------------------------------------
// K0: fused prep. blocks 0..767: conv_w fp32->bf16. blocks 768..799: normalize
// clusters v[32][256] -> bf16.  (round-0 version)
// ---------------------------------------------------------------------------
__global__ __launch_bounds__(64) void w_prep(const float* __restrict__ W,
                                             const float* __restrict__ v_in,
                                             unsigned short* __restrict__ Wb,
                                             unsigned short* __restrict__ wnb) {
    const int bx = blockIdx.x, tid = threadIdx.x;
    if (bx < 768) {
        int i = (bx * 64 + tid) * 4;
        float4 w = *(const float4*)(W + i);
        unsigned lo = (unsigned)f2bf_rne(w.x) | ((unsigned)f2bf_rne(w.y) << 16);
        unsigned hi = (unsigned)f2bf_rne(w.z) | ((unsigned)f2bf_rne(w.w) << 16);
        *(uint2*)(Wb + i) = make_uint2(lo, hi);
    } else {
        int row = bx - 768;
        float4 v = *(const float4*)(v_in + row * 256 + tid * 4);
        float s = v.x * v.x + v.y * v.y + v.z * v.z + v.w * v.w;
#pragma unroll
        for (int off = 32; off > 0; off >>= 1) s += __shfl_xor(s, off);
        float inv = 1.0f / fmaxf(sqrtf(s), 1e-12f);
        unsigned lo = (unsigned)f2bf_rne(v.x * inv) | ((unsigned)f2bf_rne(v.y * inv) << 16);
        unsigned hi = (unsigned)f2bf_rne(v.z * inv) | ((unsigned)f2bf_rne(v.w * inv) << 16);
        *(uint2*)(wnb + row * 256 + tid * 4) = make_uint2(lo, hi);
    }
}

// ---------------------------------------------------------------------------
// K1: mega kernel. IDENTICAL to round-0 except ONE mechanism: register
// prefetch of both staging load sets (W: 4x uint4, x: 8x float2) with a
// one-k-step window. Loads for tile k+1 are issued right after the ds_writes
// of tile k and consumed at the next iteration's store -- the in-flight
// window grows from ~0 to a full k-step (barrier + 12 frag reads + 32 MFMA),
// hiding the global latency that Little's-law analysis showed was the limit
// (1.5 TB/s effective from ~100B/wave in flight).
// Block: 128 n x 256 d (full), 4 waves (wn x wd).
// ---------------------------------------------------------------------------
__global__ __launch_bounds__(256) void conv_mega(const float* __restrict__ x,
                                                 const unsigned short* __restrict__ Wb,
                                                 const float* __restrict__ bias,
                                                 const unsigned short* __restrict__ wnb,
                                                 float* __restrict__ xp,
                                                 float* __restrict__ inv_norm,
                                                 float* __restrict__ Z,
                                                 float2* __restrict__ u1p) {
    __shared__ unsigned As[256 * 20];    // W tile 256d x 32k
    __shared__ unsigned Bs[128 * 17];    // x tile 128n x 32k
    __shared__ float ssq_s[128];
    __shared__ float invs_s[128];
    __shared__ unsigned xfs[128 * 33];   // xf quarter: 128n x 64d (bf16 pairs)
    __shared__ float2 upart_s[4][32];

    const int tid = threadIdx.x;
    const int lane = tid & 63;
    const int wid = tid >> 6;
    const int wn = wid & 1, wd = wid >> 1;
    const int b = blockIdx.y;
    const int n0 = blockIdx.x * 128;
    const int l15 = lane & 15, l4 = lane >> 4;
    const float* xb = x + (size_t)b * 768 * 4096;

    f32x4 acc[8][4];
#pragma unroll
    for (int i = 0; i < 8; ++i)
#pragma unroll
        for (int j = 0; j < 4; ++j) acc[i][j] = (f32x4){0.f, 0.f, 0.f, 0.f};

    // prefetch registers (one k-step ahead)
    uint4  gw[4];
    float2 gx0[4], gx1[4];

    auto LOADW = [&](int k0) {
#pragma unroll
        for (int i = 0; i < 4; ++i) {
            int f = tid + i * 256;
            int dd = f >> 2, c8 = f & 3;
            gw[i] = *(const uint4*)(Wb + (size_t)dd * 768 + k0 + c8 * 8);
        }
    };
    auto LOADX = [&](int k0) {
#pragma unroll
        for (int i = 0; i < 4; ++i) {
            int f = tid + i * 256;
            int n2 = f & 63, ch = f >> 6;
            const float* p = xb + (size_t)(k0 + 2 * ch) * 4096 + n0 + 2 * n2;
            gx0[i] = *(const float2*)p;
            gx1[i] = *(const float2*)(p + 4096);
        }
    };
    auto STORES = [&]() {
#pragma unroll
        for (int i = 0; i < 4; ++i) {
            int f = tid + i * 256;
            int dd = f >> 2, c8 = f & 3;
            *(uint4*)&As[dd * 20 + c8 * 4] = gw[i];
        }
#pragma unroll
        for (int i = 0; i < 4; ++i) {
            int f = tid + i * 256;
            int n2 = f & 63, ch = f >> 6;
            Bs[(2 * n2) * 17 + ch]     = pack_bf2(gx0[i].x, gx1[i].x);
            Bs[(2 * n2 + 1) * 17 + ch] = pack_bf2(gx0[i].y, gx1[i].y);
        }
    };

    // ---------------- phase 1: conv ----------------
    LOADW(0);
    LOADX(0);
    for (int k0 = 0; k0 < 768; k0 += 32) {
        __syncthreads();
        STORES();                            // consumes loads issued last iter
        if (k0 + 32 < 768) {                 // issue next tile's loads NOW:
            LOADW(k0 + 32);                  // they stay in flight across the
            LOADX(k0 + 32);                  // barrier + frag reads + MFMAs
        }
        __syncthreads();

        U8 af[8];
#pragma unroll
        for (int dt = 0; dt < 8; ++dt) {
            int row = wd * 128 + dt * 16 + l15;
            af[dt].q = *(uint4*)&As[row * 20 + l4 * 4];
        }
#pragma unroll
        for (int nt = 0; nt < 4; ++nt) {
            int col = wn * 64 + nt * 16 + l15;
            int base = col * 17 + l4 * 4;
            U8 bf;
            bf.u[0] = Bs[base]; bf.u[1] = Bs[base + 1];
            bf.u[2] = Bs[base + 2]; bf.u[3] = Bs[base + 3];
#pragma unroll
            for (int dt = 0; dt < 8; ++dt)
                acc[dt][nt] = __builtin_amdgcn_mfma_f32_16x16x32_bf16(
                    af[dt].v, bf.v, acc[dt][nt], 0, 0, 0);
        }
    }

    // epilogue: bias into acc, store xp, row sum-of-squares -> inv_norm
    float ssq[4] = {0.f, 0.f, 0.f, 0.f};
#pragma unroll
    for (int dt = 0; dt < 8; ++dt) {
        int d = wd * 128 + dt * 16 + l4 * 4;
        float4 bi = *(const float4*)(bias + d);
#pragma unroll
        for (int nt = 0; nt < 4; ++nt) {
            int n = n0 + wn * 64 + nt * 16 + l15;
            f32x4 o = acc[dt][nt];
            o.x += bi.x; o.y += bi.y; o.z += bi.z; o.w += bi.w;
            acc[dt][nt] = o;
            *(f32x4*)(xp + ((size_t)(b * 4096 + n)) * 256 + d) = o;
            ssq[nt] += o.x * o.x + o.y * o.y + o.z * o.z + o.w * o.w;
        }
    }
#pragma unroll
    for (int nt = 0; nt < 4; ++nt) {
        ssq[nt] += __shfl_xor(ssq[nt], 16);
        ssq[nt] += __shfl_xor(ssq[nt], 32);
    }
    if (wd == 0 && l4 == 0) {
#pragma unroll
        for (int nt = 0; nt < 4; ++nt) ssq_s[wn * 64 + nt * 16 + l15] = ssq[nt];
    }
    __syncthreads();
    if (wd == 1 && l4 == 0) {
#pragma unroll
        for (int nt = 0; nt < 4; ++nt) {
            int nl = wn * 64 + nt * 16 + l15;
            float inv = 1.0f / fmaxf(sqrtf(ssq[nt] + ssq_s[nl]), 1e-12f);
            invs_s[nl] = inv;
            inv_norm[b * 4096 + n0 + nl] = inv;
        }
    }

    // ---------------- phase 2: scores + u1 partials ----------------
    f32x4 accz[2][2];
#pragma unroll
    for (int i = 0; i < 2; ++i)
#pragma unroll
        for (int j = 0; j < 2; ++j) accz[i][j] = (f32x4){0.f, 0.f, 0.f, 0.f};

    for (int q = 0; q < 4; ++q) {
        __syncthreads();
        if (wd == (q >> 1)) {
#pragma unroll
            for (int dt4 = 0; dt4 < 4; ++dt4) {
                int dt = (q & 1) * 4 + dt4;
#pragma unroll
                for (int nt = 0; nt < 4; ++nt) {
                    int n = wn * 64 + nt * 16 + l15;
                    float inv = invs_s[n];
                    f32x4 a = acc[dt][nt];
                    int base = n * 33 + dt4 * 8 + l4 * 2;
                    xfs[base]     = pack_bf2(a.x * inv, a.y * inv);
                    xfs[base + 1] = pack_bf2(a.z * inv, a.w * inv);
                }
            }
        }
        __syncthreads();
#pragma unroll
        for (int s = 0; s < 2; ++s) {
            U8 wf[2];
#pragma unroll
            for (int mt = 0; mt < 2; ++mt)
                wf[mt].q = *(const uint4*)(wnb + (mt * 16 + l15) * 256 +
                                           q * 64 + s * 32 + l4 * 8);
#pragma unroll
            for (int sti = 0; sti < 2; ++sti) {
                int st = wid + sti * 4;
                int arow = (st * 16 + l15) * 33 + s * 16 + l4 * 4;
                U8 af;
                af.u[0] = xfs[arow]; af.u[1] = xfs[arow + 1];
                af.u[2] = xfs[arow + 2]; af.u[3] = xfs[arow + 3];
#pragma unroll
                for (int mt = 0; mt < 2; ++mt)
                    accz[sti][mt] = __builtin_amdgcn_mfma_f32_16x16x32_bf16(
                        af.v, wf[mt].v, accz[sti][mt], 0, 0, 0);
            }
        }
    }
    // scale by 1/EPS, write Z, emit u1 partials
#pragma unroll
    for (int sti = 0; sti < 2; ++sti)
#pragma unroll
        for (int mt = 0; mt < 2; ++mt) {
            accz[sti][mt].x *= 20.f; accz[sti][mt].y *= 20.f;
            accz[sti][mt].z *= 20.f; accz[sti][mt].w *= 20.f;
            int m = mt * 16 + l15;
            int st = wid + sti * 4;
            *(f32x4*)&Z[((size_t)(b * 32 + m)) * 4096 + n0 + st * 16 + l4 * 4] =
                accz[sti][mt];
        }
#pragma unroll
    for (int mt = 0; mt < 2; ++mt) {
        float v0[8] = {accz[0][mt].x, accz[0][mt].y, accz[0][mt].z, accz[0][mt].w,
                       accz[1][mt].x, accz[1][mt].y, accz[1][mt].z, accz[1][mt].w};
        float mx = v0[0];
#pragma unroll
        for (int i = 1; i < 8; ++i) mx = fmaxf(mx, v0[i]);
        float s = 0.f;
#pragma unroll
        for (int i = 0; i < 8; ++i) s += __expf(v0[i] - mx);
#pragma unroll
        for (int off = 16; off < 64; off <<= 1) {
            float omx = __shfl_xor(mx, off);
            float os = __shfl_xor(s, off);
            float nm = fmaxf(mx, omx);
            s = s * __expf(mx - nm) + os * __expf(omx - nm);
            mx = nm;
        }
        if (lane < 16) upart_s[wid][mt * 16 + lane] = make_float2(mx, s);
    }
    __syncthreads();
    if (wid == 0 && lane < 32) {
        float2 p = upart_s[0][lane];
        float mx = p.x, s = p.y;
#pragma unroll
        for (int w = 1; w < 4; ++w) {
            float2 qq = upart_s[w][lane];
            float nm = fmaxf(mx, qq.x);
            s = s * __expf(mx - nm) + qq.y * __expf(qq.x - nm);
            mx = nm;
        }
        u1p[((size_t)b * 32 + blockIdx.x) * 32 + lane] = make_float2(mx, s);
    }
}

// ---------------------------------------------------------------------------
// K2: sinkhorn v-update (round-0 version). FIRST=1: derive u from u1
// partials; else from u_g.
// ---------------------------------------------------------------------------
template <int FIRST>
__global__ __launch_bounds__(512) void sink_v(const float* __restrict__ Z,
                                              const float2* __restrict__ u1p,
                                              const float* __restrict__ u_g,
                                              float* __restrict__ v_g) {
    __shared__ float u_s[32];
    const int tid = threadIdx.x;
    const int b = blockIdx.y;
    const int n = blockIdx.x * 512 + tid;
    if (tid < 32) {
        if (FIRST) {
            float2 p = u1p[((size_t)b * 32) * 32 + tid];
            float mx = p.x, s = p.y;
#pragma unroll 4
            for (int t = 1; t < 32; ++t) {
                float2 q = u1p[((size_t)b * 32 + t) * 32 + tid];
                float nm = fmaxf(mx, q.x);
                s = s * __expf(mx - nm) + q.y * __expf(q.x - nm);
                mx = nm;
            }
            u_s[tid] = NORM_C - (mx + __logf(s));
        } else {
            u_s[tid] = u_g[b * 32 + tid];
        }
    }
    __syncthreads();
    float z[32];
#pragma unroll
    for (int m = 0; m < 32; ++m) z[m] = Z[((size_t)(b * 32 + m)) * 4096 + n] + u_s[m];
    float mx = z[0];
#pragma unroll
    for (int m = 1; m < 32; ++m) mx = fmaxf(mx, z[m]);
    float s = 0.f;
#pragma unroll
    for (int m = 0; m < 32; ++m) s += __expf(z[m] - mx);
    v_g[b * 4096 + n] = NORM_C - (mx + __logf(s));
}

// ---------------------------------------------------------------------------
// K3: sinkhorn u-update (round-0 version): one block per (b,m); LSE over
// 4096 n of Z+v.
// ---------------------------------------------------------------------------
__global__ __launch_bounds__(256) void sink_u(const float* __restrict__ Z,
                                              const float* __restrict__ v_g,
                                              float* __restrict__ u_g) {
    __shared__ float wmx[4], wsum[4];
    const int tid = threadIdx.x;
    const int lane = tid & 63, wid = tid >> 6;
    const int b = blockIdx.x >> 5, m = blockIdx.x & 31;
    const float* zr = Z + ((size_t)(b * 32 + m)) * 4096;
    const float* vr = v_g + b * 4096;

    float z[16];
#pragma unroll
    for (int j = 0; j < 16; ++j) {
        int n = tid + j * 256;
        z[j] = zr[n] + vr[n];
    }
    float mx = z[0];
#pragma unroll
    for (int j = 1; j < 16; ++j) mx = fmaxf(mx, z[j]);
    float s = 0.f;
#pragma unroll
    for (int j = 0; j < 16; ++j) s += __expf(z[j] - mx);
#pragma unroll
    for (int off = 1; off < 64; off <<= 1) {
        float omx = __shfl_xor(mx, off);
        float os = __shfl_xor(s, off);
        float nm = fmaxf(mx, omx);
        s = s * __expf(mx - nm) + os * __expf(omx - nm);
        mx = nm;
    }
    if (lane == 0) { wmx[wid] = mx; wsum[wid] = s; }
    __syncthreads();
    if (tid == 0) {
        float gm = wmx[0], gs = wsum[0];
#pragma unroll
        for (int w = 1; w < 4; ++w) {
            float nm = fmaxf(gm, wmx[w]);
            gs = gs * __expf(gm - nm) + wsum[w] * __expf(wmx[w] - nm);
            gm = nm;
        }
        u_g[b * 32 + m] = NORM_C - (gm + __logf(gs));
    }
}

// ---------------------------------------------------------------------------
// K4: v_tilde partials (round-0 version). v3 computed inline from u3 (= u_g).
// Block: (chunk of 256 n x d-half 128, b). Thread: 4 d x 4 m.
// ---------------------------------------------------------------------------
__global__ __launch_bounds__(256) void vtilde_part_k(const float* __restrict__ xp,
                                                     const float* __restrict__ inv_norm,
                                                     const float* __restrict__ Z,
                                                     const float* __restrict__ u_g,
                                                     float* __restrict__ part) {
    __shared__ float u_s[32];
    __shared__ float v3_s[256];
    __shared__ float inv_s[256];
    __shared__ float wt[64 * 36];
    const int tid = threadIdx.x;
    const int cx = blockIdx.x;
    const int chunk = cx >> 1, dh = cx & 1;
    const int b = blockIdx.y;
    const int n0 = chunk * 256;
    if (tid < 32) u_s[tid] = u_g[b * 32 + tid];
    __syncthreads();
    {
        int n = n0 + tid;
        float z[32];
#pragma unroll
        for (int m = 0; m < 32; ++m)
            z[m] = Z[((size_t)(b * 32 + m)) * 4096 + n] + u_s[m];
        float mx = z[0];
#pragma unroll
        for (int m = 1; m < 32; ++m) mx = fmaxf(mx, z[m]);
        float s = 0.f;
#pragma unroll
        for (int m = 0; m < 32; ++m) s += __expf(z[m] - mx);
        v3_s[tid] = NORM_C - (mx + __logf(s));
        inv_s[tid] = inv_norm[b * 4096 + n];
    }
    __syncthreads();

    const int dg = tid & 31, mq = tid >> 5;
    f32x4 acc[4];
#pragma unroll
    for (int j = 0; j < 4; ++j) acc[j] = (f32x4){0.f, 0.f, 0.f, 0.f};
    const float* xpb = xp + ((size_t)(b * 4096 + n0)) * 256 + dh * 128 + dg * 4;

    for (int t = 0; t < 4; ++t) {
#pragma unroll
        for (int i = 0; i < 8; ++i) {
            int e = tid + i * 256;
            int mW = e >> 6, nn = e & 63;
            int nl = t * 64 + nn;
            wt[nn * 36 + mW] =
                __expf(Z[((size_t)(b * 32 + mW)) * 4096 + n0 + nl] + u_s[mW] +
                       v3_s[nl] - NORM_C) * inv_s[nl];
        }
        __syncthreads();
#pragma unroll 4
        for (int nn = 0; nn < 64; ++nn) {
            float4 xv = *(const float4*)(xpb + (size_t)(t * 64 + nn) * 256);
            float4 wv = *(const float4*)&wt[nn * 36 + mq * 4];
            acc[0].x += wv.x * xv.x; acc[0].y += wv.x * xv.y; acc[0].z += wv.x * xv.z; acc[0].w += wv.x * xv.w;
            acc[1].x += wv.y * xv.x; acc[1].y += wv.y * xv.y; acc[1].z += wv.y * xv.z; acc[1].w += wv.y * xv.w;
            acc[2].x += wv.z * xv.x; acc[2].y += wv.z * xv.y; acc[2].z += wv.z * xv.z; acc[2].w += wv.z * xv.w;
            acc[3].x += wv.w * xv.x; acc[3].y += wv.w * xv.y; acc[3].z += wv.w * xv.z; acc[3].w += wv.w * xv.w;
        }
        __syncthreads();
    }
#pragma unroll
    for (int j = 0; j < 4; ++j) {
        int m = mq * 4 + j;
        *(f32x4*)&part[((size_t)(b * 16 + chunk)) * 8192 + m * 256 + dh * 128 + dg * 4] = acc[j];
    }
}

// ---------------------------------------------------------------------------
// K5: reduce 16 chunk-partials -> v_tilde
// ---------------------------------------------------------------------------
__global__ __launch_bounds__(256) void vtilde_reduce(const float* __restrict__ part,
                                                     float* __restrict__ out_vt) {
    int o = blockIdx.x * 256 + threadIdx.x;
    int b = o >> 13, r = o & 8191;
    float s = 0.f;
#pragma unroll
    for (int c = 0; c < 16; ++c)
        s += part[((size_t)(b * 16 + c)) * 8192 + r];
    out_vt[o] = s;
}

// ---------------------------------------------------------------------------
extern "C" void kernel_launch(void* const* d_in, const int* in_sizes, int n_in,
                              void* d_out, int out_size, void* d_ws, size_t ws_size,
                              hipStream_t stream) {
    const float* x      = (const float*)d_in[0];
    const float* conv_w = (const float*)d_in[1];
    const float* conv_b = (const float*)d_in[2];
    const float* v_in   = (const float*)d_in[3];

    float* out_vt = (float*)d_out;                 // [16][32][256]
    float* out_xp = (float*)d_out + 131072;        // [16][4096][256]

    float* ws = (float*)d_ws;
    float*          inv_norm = ws;                                  // 65536
    unsigned short* Wb       = (unsigned short*)(ws + 65536);       // 196608 bf16
    unsigned short* wnb      = (unsigned short*)(ws + 163840);      // 8192 bf16
    float*          Zbuf     = ws + 167936;                         // 2097152
    float2*         u1p      = (float2*)(ws + 2265088);             // 16384 float2
    float*          u_g      = ws + 2297856;                        // 512
    float*          v_g      = ws + 2298368;                        // 65536
    float*          part     = ws + 2363904;                        // 2097152

    w_prep<<<800, 64, 0, stream>>>(conv_w, v_in, Wb, wnb);
    conv_mega<<<dim3(32, 16), 256, 0, stream>>>(x, Wb, conv_b, wnb, out_xp,
                                                inv_norm, Zbuf, u1p);
    sink_v<1><<<dim3(8, 16), 512, 0, stream>>>(Zbuf, u1p, u_g, v_g);   // v1 (u1 from partials)
    sink_u<<<512, 256, 0, stream>>>(Zbuf, v_g, u_g);                   // u2
    sink_v<0><<<dim3(8, 16), 512, 0, stream>>>(Zbuf, u1p, u_g, v_g);   // v2
    sink_u<<<512, 256, 0, stream>>>(Zbuf, v_g, u_g);                   // u3
    vtilde_part_k<<<dim3(32, 16), 256, 0, stream>>>(out_xp, inv_norm, Zbuf, u_g, part);
    vtilde_reduce<<<512, 256, 0, stream>>>(part, out_vt);
}

// Round 6
// 360.071 us; speedup vs baseline: 1.1324x; 1.1324x over previous
//
#include <hip/hip_runtime.h>
#include <math.h>

#define NORM_C (-8.3255483f)   /* -log(32+4096) */

typedef __attribute__((ext_vector_type(8))) short bf16x8;
typedef __attribute__((ext_vector_type(4))) float f32x4;

union U8 { uint4 q; unsigned u[4]; bf16x8 v; };

__device__ inline unsigned short f2bf_rne(float f) {
    unsigned u = __float_as_uint(f);
    unsigned r = u + 0x7fffu + ((u >> 16) & 1u);
    return (unsigned short)(r >> 16);
}
// pack two floats -> (bf16(hi)<<16)|bf16(lo)
__device__ inline unsigned pack_bf2(float lo, float hi) {
    unsigned a = __float_as_uint(lo) + 0x8000u;
    unsigned b = __float_as_uint(hi) + 0x8000u;
    return __builtin_amdgcn_perm(b, a, 0x07060302u);
}

// Raw workgroup barrier WITHOUT the vmcnt drain __syncthreads() forces.
// lgkmcnt(0) makes LDS writes visible; global loads stay in flight across.
// Trailing empty asm pins later LDS reads below the barrier.
#define RAW_BARRIER() do {                                   \
    asm volatile("s_waitcnt lgkmcnt(0)" ::: "memory");       \
    __builtin_amdgcn_s_barrier();                            \
    asm volatile("" ::: "memory");                           \
} while (0)

// ---------------------------------------------------------------------------
// K0: fused prep. blocks 0..767: conv_w fp32->bf16. blocks 768..799: normalize
// clusters v[32][256] -> bf16.  (round-0 version)
// ---------------------------------------------------------------------------
__global__ __launch_bounds__(64) void w_prep(const float* __restrict__ W,
                                             const float* __restrict__ v_in,
                                             unsigned short* __restrict__ Wb,
                                             unsigned short* __restrict__ wnb) {
    const int bx = blockIdx.x, tid = threadIdx.x;
    if (bx < 768) {
        int i = (bx * 64 + tid) * 4;
        float4 w = *(const float4*)(W + i);
        unsigned lo = (unsigned)f2bf_rne(w.x) | ((unsigned)f2bf_rne(w.y) << 16);
        unsigned hi = (unsigned)f2bf_rne(w.z) | ((unsigned)f2bf_rne(w.w) << 16);
        *(uint2*)(Wb + i) = make_uint2(lo, hi);
    } else {
        int row = bx - 768;
        float4 v = *(const float4*)(v_in + row * 256 + tid * 4);
        float s = v.x * v.x + v.y * v.y + v.z * v.z + v.w * v.w;
#pragma unroll
        for (int off = 32; off > 0; off >>= 1) s += __shfl_xor(s, off);
        float inv = 1.0f / fmaxf(sqrtf(s), 1e-12f);
        unsigned lo = (unsigned)f2bf_rne(v.x * inv) | ((unsigned)f2bf_rne(v.y * inv) << 16);
        unsigned hi = (unsigned)f2bf_rne(v.z * inv) | ((unsigned)f2bf_rne(v.w * inv) << 16);
        *(uint2*)(wnb + row * 256 + tid * 4) = make_uint2(lo, hi);
    }
}

// ---------------------------------------------------------------------------
// K1: mega kernel. Round-0 structure and layouts; three changes only:
//  (1) x staged via one-k-step register prefetch (gx, issued after this
//      step's ds_writes, consumed at next step's pack): in-flight window =
//      barrier + frag reads + 32 MFMA + barrier > HBM latency.
//  (2) k-loop barriers are RAW (no vmcnt drain) -- __syncthreads() would
//      force s_waitcnt vmcnt(0) at the barrier and kill (1) (round-5 lesson).
//  (3) MFMA fragment loop inverted (hold bf[4]=16 regs, af per-dt) to offset
//      the +16 prefetch VGPRs -> net register demand ~= round-0, no spills.
// W staging stays same-phase (L2-hot, ~200cyc; prefetching it spilled in R5).
// Block: 128 n x 256 d (full), 4 waves (wn x wd).
// ---------------------------------------------------------------------------
__global__ __launch_bounds__(256) void conv_mega(const float* __restrict__ x,
                                                 const unsigned short* __restrict__ Wb,
                                                 const float* __restrict__ bias,
                                                 const unsigned short* __restrict__ wnb,
                                                 float* __restrict__ xp,
                                                 float* __restrict__ inv_norm,
                                                 float* __restrict__ Z,
                                                 float2* __restrict__ u1p) {
    __shared__ unsigned As[256 * 20];    // W tile 256d x 32k
    __shared__ unsigned Bs[128 * 17];    // x tile 128n x 32k
    __shared__ float ssq_s[128];
    __shared__ float invs_s[128];
    __shared__ unsigned xfs[128 * 33];   // xf quarter: 128n x 64d (bf16 pairs)
    __shared__ float2 upart_s[4][32];

    const int tid = threadIdx.x;
    const int lane = tid & 63;
    const int wid = tid >> 6;
    const int wn = wid & 1, wd = wid >> 1;
    const int b = blockIdx.y;
    const int n0 = blockIdx.x * 128;
    const int l15 = lane & 15, l4 = lane >> 4;
    const float* xb = x + (size_t)b * 768 * 4096;

    f32x4 acc[8][4];
#pragma unroll
    for (int i = 0; i < 8; ++i)
#pragma unroll
        for (int j = 0; j < 4; ++j) acc[i][j] = (f32x4){0.f, 0.f, 0.f, 0.f};

    // x prefetch registers (one k-step ahead)
    float2 gx0[4], gx1[4];
    auto ISSUE_X = [&](int k0) {
#pragma unroll
        for (int i = 0; i < 4; ++i) {
            int f = tid + i * 256;
            int n2 = f & 63, ch = f >> 6;
            const float* p = xb + (size_t)(k0 + 2 * ch) * 4096 + n0 + 2 * n2;
            gx0[i] = *(const float2*)p;
            gx1[i] = *(const float2*)(p + 4096);
        }
    };

    // ---------------- phase 1: conv ----------------
    ISSUE_X(0);
    for (int k0 = 0; k0 < 768; k0 += 32) {
        RAW_BARRIER();                       // prev tile's frag reads done
        // W stage (same-phase, L2-hot)
#pragma unroll
        for (int i = 0; i < 4; ++i) {
            int f = tid + i * 256;
            int dd = f >> 2, c8 = f & 3;
            uint4 w = *(const uint4*)(Wb + (size_t)dd * 768 + k0 + c8 * 8);
            *(uint4*)&As[dd * 20 + c8 * 4] = w;
        }
        // x store from regs prefetched one k-step ago
#pragma unroll
        for (int i = 0; i < 4; ++i) {
            int f = tid + i * 256;
            int n2 = f & 63, ch = f >> 6;
            Bs[(2 * n2) * 17 + ch]     = pack_bf2(gx0[i].x, gx1[i].x);
            Bs[(2 * n2 + 1) * 17 + ch] = pack_bf2(gx0[i].y, gx1[i].y);
        }
        if (k0 + 32 < 768) ISSUE_X(k0 + 32); // stays in flight across barrier
        RAW_BARRIER();                       // staging visible; NO vmcnt drain

        U8 bf[4];
#pragma unroll
        for (int nt = 0; nt < 4; ++nt) {
            int col = wn * 64 + nt * 16 + l15;
            int base = col * 17 + l4 * 4;
            bf[nt].u[0] = Bs[base];     bf[nt].u[1] = Bs[base + 1];
            bf[nt].u[2] = Bs[base + 2]; bf[nt].u[3] = Bs[base + 3];
        }
#pragma unroll
        for (int dt = 0; dt < 8; ++dt) {
            int row = wd * 128 + dt * 16 + l15;
            U8 af;
            af.q = *(uint4*)&As[row * 20 + l4 * 4];
#pragma unroll
            for (int nt = 0; nt < 4; ++nt)
                acc[dt][nt] = __builtin_amdgcn_mfma_f32_16x16x32_bf16(
                    af.v, bf[nt].v, acc[dt][nt], 0, 0, 0);
        }
    }

    // epilogue: bias into acc, store xp, row sum-of-squares -> inv_norm
    float ssq[4] = {0.f, 0.f, 0.f, 0.f};
#pragma unroll
    for (int dt = 0; dt < 8; ++dt) {
        int d = wd * 128 + dt * 16 + l4 * 4;
        float4 bi = *(const float4*)(bias + d);
#pragma unroll
        for (int nt = 0; nt < 4; ++nt) {
            int n = n0 + wn * 64 + nt * 16 + l15;
            f32x4 o = acc[dt][nt];
            o.x += bi.x; o.y += bi.y; o.z += bi.z; o.w += bi.w;
            acc[dt][nt] = o;
            *(f32x4*)(xp + ((size_t)(b * 4096 + n)) * 256 + d) = o;
            ssq[nt] += o.x * o.x + o.y * o.y + o.z * o.z + o.w * o.w;
        }
    }
#pragma unroll
    for (int nt = 0; nt < 4; ++nt) {
        ssq[nt] += __shfl_xor(ssq[nt], 16);
        ssq[nt] += __shfl_xor(ssq[nt], 32);
    }
    if (wd == 0 && l4 == 0) {
#pragma unroll
        for (int nt = 0; nt < 4; ++nt) ssq_s[wn * 64 + nt * 16 + l15] = ssq[nt];
    }
    __syncthreads();
    if (wd == 1 && l4 == 0) {
#pragma unroll
        for (int nt = 0; nt < 4; ++nt) {
            int nl = wn * 64 + nt * 16 + l15;
            float inv = 1.0f / fmaxf(sqrtf(ssq[nt] + ssq_s[nl]), 1e-12f);
            invs_s[nl] = inv;
            inv_norm[b * 4096 + n0 + nl] = inv;
        }
    }

    // ---------------- phase 2: scores + u1 partials ----------------
    f32x4 accz[2][2];
#pragma unroll
    for (int i = 0; i < 2; ++i)
#pragma unroll
        for (int j = 0; j < 2; ++j) accz[i][j] = (f32x4){0.f, 0.f, 0.f, 0.f};

    for (int q = 0; q < 4; ++q) {
        __syncthreads();
        if (wd == (q >> 1)) {
#pragma unroll
            for (int dt4 = 0; dt4 < 4; ++dt4) {
                int dt = (q & 1) * 4 + dt4;
#pragma unroll
                for (int nt = 0; nt < 4; ++nt) {
                    int n = wn * 64 + nt * 16 + l15;
                    float inv = invs_s[n];
                    f32x4 a = acc[dt][nt];
                    int base = n * 33 + dt4 * 8 + l4 * 2;
                    xfs[base]     = pack_bf2(a.x * inv, a.y * inv);
                    xfs[base + 1] = pack_bf2(a.z * inv, a.w * inv);
                }
            }
        }
        __syncthreads();
#pragma unroll
        for (int s = 0; s < 2; ++s) {
            U8 wf[2];
#pragma unroll
            for (int mt = 0; mt < 2; ++mt)
                wf[mt].q = *(const uint4*)(wnb + (mt * 16 + l15) * 256 +
                                           q * 64 + s * 32 + l4 * 8);
#pragma unroll
            for (int sti = 0; sti < 2; ++sti) {
                int st = wid + sti * 4;
                int arow = (st * 16 + l15) * 33 + s * 16 + l4 * 4;
                U8 af;
                af.u[0] = xfs[arow]; af.u[1] = xfs[arow + 1];
                af.u[2] = xfs[arow + 2]; af.u[3] = xfs[arow + 3];
#pragma unroll
                for (int mt = 0; mt < 2; ++mt)
                    accz[sti][mt] = __builtin_amdgcn_mfma_f32_16x16x32_bf16(
                        af.v, wf[mt].v, accz[sti][mt], 0, 0, 0);
            }
        }
    }
    // scale by 1/EPS, write Z, emit u1 partials
#pragma unroll
    for (int sti = 0; sti < 2; ++sti)
#pragma unroll
        for (int mt = 0; mt < 2; ++mt) {
            accz[sti][mt].x *= 20.f; accz[sti][mt].y *= 20.f;
            accz[sti][mt].z *= 20.f; accz[sti][mt].w *= 20.f;
            int m = mt * 16 + l15;
            int st = wid + sti * 4;
            *(f32x4*)&Z[((size_t)(b * 32 + m)) * 4096 + n0 + st * 16 + l4 * 4] =
                accz[sti][mt];
        }
#pragma unroll
    for (int mt = 0; mt < 2; ++mt) {
        float v0[8] = {accz[0][mt].x, accz[0][mt].y, accz[0][mt].z, accz[0][mt].w,
                       accz[1][mt].x, accz[1][mt].y, accz[1][mt].z, accz[1][mt].w};
        float mx = v0[0];
#pragma unroll
        for (int i = 1; i < 8; ++i) mx = fmaxf(mx, v0[i]);
        float s = 0.f;
#pragma unroll
        for (int i = 0; i < 8; ++i) s += __expf(v0[i] - mx);
#pragma unroll
        for (int off = 16; off < 64; off <<= 1) {
            float omx = __shfl_xor(mx, off);
            float os = __shfl_xor(s, off);
            float nm = fmaxf(mx, omx);
            s = s * __expf(mx - nm) + os * __expf(omx - nm);
            mx = nm;
        }
        if (lane < 16) upart_s[wid][mt * 16 + lane] = make_float2(mx, s);
    }
    __syncthreads();
    if (wid == 0 && lane < 32) {
        float2 p = upart_s[0][lane];
        float mx = p.x, s = p.y;
#pragma unroll
        for (int w = 1; w < 4; ++w) {
            float2 qq = upart_s[w][lane];
            float nm = fmaxf(mx, qq.x);
            s = s * __expf(mx - nm) + qq.y * __expf(qq.x - nm);
            mx = nm;
        }
        u1p[((size_t)b * 32 + blockIdx.x) * 32 + lane] = make_float2(mx, s);
    }
}

// ---------------------------------------------------------------------------
// K2: sinkhorn v-update (round-0 version). FIRST=1: derive u from u1
// partials; else from u_g.
// ---------------------------------------------------------------------------
template <int FIRST>
__global__ __launch_bounds__(512) void sink_v(const float* __restrict__ Z,
                                              const float2* __restrict__ u1p,
                                              const float* __restrict__ u_g,
                                              float* __restrict__ v_g) {
    __shared__ float u_s[32];
    const int tid = threadIdx.x;
    const int b = blockIdx.y;
    const int n = blockIdx.x * 512 + tid;
    if (tid < 32) {
        if (FIRST) {
            float2 p = u1p[((size_t)b * 32) * 32 + tid];
            float mx = p.x, s = p.y;
#pragma unroll 4
            for (int t = 1; t < 32; ++t) {
                float2 q = u1p[((size_t)b * 32 + t) * 32 + tid];
                float nm = fmaxf(mx, q.x);
                s = s * __expf(mx - nm) + q.y * __expf(q.x - nm);
                mx = nm;
            }
            u_s[tid] = NORM_C - (mx + __logf(s));
        } else {
            u_s[tid] = u_g[b * 32 + tid];
        }
    }
    __syncthreads();
    float z[32];
#pragma unroll
    for (int m = 0; m < 32; ++m) z[m] = Z[((size_t)(b * 32 + m)) * 4096 + n] + u_s[m];
    float mx = z[0];
#pragma unroll
    for (int m = 1; m < 32; ++m) mx = fmaxf(mx, z[m]);
    float s = 0.f;
#pragma unroll
    for (int m = 0; m < 32; ++m) s += __expf(z[m] - mx);
    v_g[b * 4096 + n] = NORM_C - (mx + __logf(s));
}

// ---------------------------------------------------------------------------
// K3: sinkhorn u-update (round-0 version): one block per (b,m); LSE over
// 4096 n of Z+v.
// ---------------------------------------------------------------------------
__global__ __launch_bounds__(256) void sink_u(const float* __restrict__ Z,
                                              const float* __restrict__ v_g,
                                              float* __restrict__ u_g) {
    __shared__ float wmx[4], wsum[4];
    const int tid = threadIdx.x;
    const int lane = tid & 63, wid = tid >> 6;
    const int b = blockIdx.x >> 5, m = blockIdx.x & 31;
    const float* zr = Z + ((size_t)(b * 32 + m)) * 4096;
    const float* vr = v_g + b * 4096;

    float z[16];
#pragma unroll
    for (int j = 0; j < 16; ++j) {
        int n = tid + j * 256;
        z[j] = zr[n] + vr[n];
    }
    float mx = z[0];
#pragma unroll
    for (int j = 1; j < 16; ++j) mx = fmaxf(mx, z[j]);
    float s = 0.f;
#pragma unroll
    for (int j = 0; j < 16; ++j) s += __expf(z[j] - mx);
#pragma unroll
    for (int off = 1; off < 64; off <<= 1) {
        float omx = __shfl_xor(mx, off);
        float os = __shfl_xor(s, off);
        float nm = fmaxf(mx, omx);
        s = s * __expf(mx - nm) + os * __expf(omx - nm);
        mx = nm;
    }
    if (lane == 0) { wmx[wid] = mx; wsum[wid] = s; }
    __syncthreads();
    if (tid == 0) {
        float gm = wmx[0], gs = wsum[0];
#pragma unroll
        for (int w = 1; w < 4; ++w) {
            float nm = fmaxf(gm, wmx[w]);
            gs = gs * __expf(gm - nm) + wsum[w] * __expf(wmx[w] - nm);
            gm = nm;
        }
        u_g[b * 32 + m] = NORM_C - (gm + __logf(gs));
    }
}

// ---------------------------------------------------------------------------
// K4: v_tilde partials (round-0 version). v3 computed inline from u3 (= u_g).
// Block: (chunk of 256 n x d-half 128, b). Thread: 4 d x 4 m.
// ---------------------------------------------------------------------------
__global__ __launch_bounds__(256) void vtilde_part_k(const float* __restrict__ xp,
                                                     const float* __restrict__ inv_norm,
                                                     const float* __restrict__ Z,
                                                     const float* __restrict__ u_g,
                                                     float* __restrict__ part) {
    __shared__ float u_s[32];
    __shared__ float v3_s[256];
    __shared__ float inv_s[256];
    __shared__ float wt[64 * 36];
    const int tid = threadIdx.x;
    const int cx = blockIdx.x;
    const int chunk = cx >> 1, dh = cx & 1;
    const int b = blockIdx.y;
    const int n0 = chunk * 256;
    if (tid < 32) u_s[tid] = u_g[b * 32 + tid];
    __syncthreads();
    {
        int n = n0 + tid;
        float z[32];
#pragma unroll
        for (int m = 0; m < 32; ++m)
            z[m] = Z[((size_t)(b * 32 + m)) * 4096 + n] + u_s[m];
        float mx = z[0];
#pragma unroll
        for (int m = 1; m < 32; ++m) mx = fmaxf(mx, z[m]);
        float s = 0.f;
#pragma unroll
        for (int m = 0; m < 32; ++m) s += __expf(z[m] - mx);
        v3_s[tid] = NORM_C - (mx + __logf(s));
        inv_s[tid] = inv_norm[b * 4096 + n];
    }
    __syncthreads();

    const int dg = tid & 31, mq = tid >> 5;
    f32x4 acc[4];
#pragma unroll
    for (int j = 0; j < 4; ++j) acc[j] = (f32x4){0.f, 0.f, 0.f, 0.f};
    const float* xpb = xp + ((size_t)(b * 4096 + n0)) * 256 + dh * 128 + dg * 4;

    for (int t = 0; t < 4; ++t) {
#pragma unroll
        for (int i = 0; i < 8; ++i) {
            int e = tid + i * 256;
            int mW = e >> 6, nn = e & 63;
            int nl = t * 64 + nn;
            wt[nn * 36 + mW] =
                __expf(Z[((size_t)(b * 32 + mW)) * 4096 + n0 + nl] + u_s[mW] +
                       v3_s[nl] - NORM_C) * inv_s[nl];
        }
        __syncthreads();
#pragma unroll 4
        for (int nn = 0; nn < 64; ++nn) {
            float4 xv = *(const float4*)(xpb + (size_t)(t * 64 + nn) * 256);
            float4 wv = *(const float4*)&wt[nn * 36 + mq * 4];
            acc[0].x += wv.x * xv.x; acc[0].y += wv.x * xv.y; acc[0].z += wv.x * xv.z; acc[0].w += wv.x * xv.w;
            acc[1].x += wv.y * xv.x; acc[1].y += wv.y * xv.y; acc[1].z += wv.y * xv.z; acc[1].w += wv.y * xv.w;
            acc[2].x += wv.z * xv.x; acc[2].y += wv.z * xv.y; acc[2].z += wv.z * xv.z; acc[2].w += wv.z * xv.w;
            acc[3].x += wv.w * xv.x; acc[3].y += wv.w * xv.y; acc[3].z += wv.w * xv.z; acc[3].w += wv.w * xv.w;
        }
        __syncthreads();
    }
#pragma unroll
    for (int j = 0; j < 4; ++j) {
        int m = mq * 4 + j;
        *(f32x4*)&part[((size_t)(b * 16 + chunk)) * 8192 + m * 256 + dh * 128 + dg * 4] = acc[j];
    }
}

// ---------------------------------------------------------------------------
// K5: reduce 16 chunk-partials -> v_tilde
// ---------------------------------------------------------------------------
__global__ __launch_bounds__(256) void vtilde_reduce(const float* __restrict__ part,
                                                     float* __restrict__ out_vt) {
    int o = blockIdx.x * 256 + threadIdx.x;
    int b = o >> 13, r = o & 8191;
    float s = 0.f;
#pragma unroll
    for (int c = 0; c < 16; ++c)
        s += part[((size_t)(b * 16 + c)) * 8192 + r];
    out_vt[o] = s;
}

// ---------------------------------------------------------------------------
extern "C" void kernel_launch(void* const* d_in, const int* in_sizes, int n_in,
                              void* d_out, int out_size, void* d_ws, size_t ws_size,
                              hipStream_t stream) {
    const float* x      = (const float*)d_in[0];
    const float* conv_w = (const float*)d_in[1];
    const float* conv_b = (const float*)d_in[2];
    const float* v_in   = (const float*)d_in[3];

    float* out_vt = (float*)d_out;                 // [16][32][256]
    float* out_xp = (float*)d_out + 131072;        // [16][4096][256]

    float* ws = (float*)d_ws;
    float*          inv_norm = ws;                                  // 65536
    unsigned short* Wb       = (unsigned short*)(ws + 65536);       // 196608 bf16
    unsigned short* wnb      = (unsigned short*)(ws + 163840);      // 8192 bf16
    float*          Zbuf     = ws + 167936;                         // 2097152
    float2*         u1p      = (float2*)(ws + 2265088);             // 16384 float2
    float*          u_g      = ws + 2297856;                        // 512
    float*          v_g      = ws + 2298368;                        // 65536
    float*          part     = ws + 2363904;                        // 2097152

    w_prep<<<800, 64, 0, stream>>>(conv_w, v_in, Wb, wnb);
    conv_mega<<<dim3(32, 16), 256, 0, stream>>>(x, Wb, conv_b, wnb, out_xp,
                                                inv_norm, Zbuf, u1p);
    sink_v<1><<<dim3(8, 16), 512, 0, stream>>>(Zbuf, u1p, u_g, v_g);   // v1 (u1 from partials)
    sink_u<<<512, 256, 0, stream>>>(Zbuf, v_g, u_g);                   // u2
    sink_v<0><<<dim3(8, 16), 512, 0, stream>>>(Zbuf, u1p, u_g, v_g);   // v2
    sink_u<<<512, 256, 0, stream>>>(Zbuf, v_g, u_g);                   // u3
    vtilde_part_k<<<dim3(32, 16), 256, 0, stream>>>(out_xp, inv_norm, Zbuf, u_g, part);
    vtilde_reduce<<<512, 256, 0, stream>>>(part, out_vt);
}